// Round 2
// baseline (1184.394 us; speedup 1.0000x reference)
//
#include <hip/hip_runtime.h>

typedef unsigned short u16;
typedef unsigned int   u32;
typedef __bf16 bfx8 __attribute__((ext_vector_type(8)));
typedef float  fx4  __attribute__((ext_vector_type(4)));

__device__ __forceinline__ u16 f2b(float f) {
    union { float f; u32 i; } v; v.f = f;
    u32 r = (v.i + 0x7fffu + ((v.i >> 16) & 1u)) >> 16;
    return (u16)r;
}
__device__ __forceinline__ u32 pk(float a, float b) {
    return (u32)f2b(a) | ((u32)f2b(b) << 16);
}

// partitioned row r (window-major) -> token index in [0,32768), with roll shift
__device__ __forceinline__ int map_token(int r, int shift) {
    int win = r >> 6, n = r & 63;
    int wh = win >> 6, ww = (win >> 3) & 7, wt = win & 7;
    int h = wh * 4 + (n >> 4);
    int w = ww * 4 + ((n >> 2) & 3);
    int t = wt * 4 + (n & 3);
    h = (h + shift) & 31; w = (w + shift) & 31; t = (t + shift) & 31;
    return (h << 10) | (w << 5) | t;
}

// ---------- batched fp32 -> bf16 weight conversion ----------
struct CvtArgs { const float* src[8]; int cum[9]; };
__global__ __launch_bounds__(256) void cvt_kernel(CvtArgs a, u16* __restrict__ dst) {
    int g = (blockIdx.x * 256 + threadIdx.x) * 4;
    int t = 0;
    #pragma unroll
    for (int i = 1; i < 8; i++) t += (g >= a.cum[i]);
    int local = g - a.cum[t];
    float4 f = *(const float4*)(a.src[t] + local);
    uint2 o; o.x = pk(f.x, f.y); o.y = pk(f.z, f.w);
    *(uint2*)(dst + g) = o;
}

// ---------- LayerNorm (one wave per token). GATHER: out row partitioned, input gathered ----------
template<int GATHER, int F32OUT>
__global__ __launch_bounds__(256) void ln_kernel(const float* __restrict__ resid,
                                                 const float* __restrict__ g, const float* __restrict__ b,
                                                 void* __restrict__ outp, int shift) {
    int lane = threadIdx.x & 63;
    int row  = blockIdx.x * 4 + (threadIdx.x >> 6);
    int src  = GATHER ? map_token(row, shift) : row;
    float4 x = ((const float4*)(resid + src * 256))[lane];
    float s1 = x.x + x.y + x.z + x.w;
    float s2 = x.x * x.x + x.y * x.y + x.z * x.z + x.w * x.w;
    #pragma unroll
    for (int off = 1; off < 64; off <<= 1) { s1 += __shfl_xor(s1, off); s2 += __shfl_xor(s2, off); }
    float mean = s1 * (1.0f / 256.0f);
    float var  = s2 * (1.0f / 256.0f) - mean * mean;
    float rstd = rsqrtf(var + 1e-5f);
    int c = lane * 4;
    float4 gv = *(const float4*)(g + c);
    float4 bv = *(const float4*)(b + c);
    float y0 = (x.x - mean) * rstd * gv.x + bv.x;
    float y1 = (x.y - mean) * rstd * gv.y + bv.y;
    float y2 = (x.z - mean) * rstd * gv.z + bv.z;
    float y3 = (x.w - mean) * rstd * gv.w + bv.w;
    if (F32OUT) {
        float4 o; o.x = y0; o.y = y1; o.z = y2; o.w = y3;
        *(float4*)((float*)outp + row * 256 + c) = o;
    } else {
        uint2 o; o.x = pk(y0, y1); o.y = pk(y2, y3);
        *(uint2*)((u16*)outp + row * 256 + c) = o;
    }
}

// ---------- GEMM: C[M,N] = A[M,K] @ W[N,K]^T + bias (A, W bf16; accum fp32) ----------
// EPI 0: bf16 store; 1: GELU + bf16 store; 2: resid[r*256+c]+=v; 3: resid[map_token(r,shift)*256+c]+=v
template<int EPI>
__global__ __launch_bounds__(256) void gemm_kernel(const u16* __restrict__ A, const u16* __restrict__ W,
                                                   const float* __restrict__ bias,
                                                   u16* __restrict__ outb, float* __restrict__ resid,
                                                   int Nout, int K, int shift) {
    int lane = threadIdx.x & 63;
    int wid  = threadIdx.x >> 6;
    int m0 = blockIdx.x * 64 + (wid >> 1) * 32;
    int n0 = blockIdx.y * 64 + (wid & 1) * 32;
    int lr = lane & 15;
    int ko = (lane >> 4) * 8;
    fx4 acc[2][2] = {};
    const u16* Ap0 = A + (m0 + lr) * K + ko;
    const u16* Ap1 = Ap0 + 16 * K;
    const u16* Bp0 = W + (n0 + lr) * K + ko;
    const u16* Bp1 = Bp0 + 16 * K;
    for (int k = 0; k < K; k += 32) {
        bfx8 a0 = *(const bfx8*)(Ap0 + k);
        bfx8 a1 = *(const bfx8*)(Ap1 + k);
        bfx8 b0 = *(const bfx8*)(Bp0 + k);
        bfx8 b1 = *(const bfx8*)(Bp1 + k);
        acc[0][0] = __builtin_amdgcn_mfma_f32_16x16x32_bf16(a0, b0, acc[0][0], 0, 0, 0);
        acc[0][1] = __builtin_amdgcn_mfma_f32_16x16x32_bf16(a0, b1, acc[0][1], 0, 0, 0);
        acc[1][0] = __builtin_amdgcn_mfma_f32_16x16x32_bf16(a1, b0, acc[1][0], 0, 0, 0);
        acc[1][1] = __builtin_amdgcn_mfma_f32_16x16x32_bf16(a1, b1, acc[1][1], 0, 0, 0);
    }
    int drow = (lane >> 4) * 4;
    int dcol = lane & 15;
    #pragma unroll
    for (int j = 0; j < 2; j++) {
        int gc = n0 + j * 16 + dcol;
        float bv = bias[gc];
        #pragma unroll
        for (int i = 0; i < 2; i++) {
            #pragma unroll
            for (int r = 0; r < 4; r++) {
                int gr = m0 + i * 16 + drow + r;
                float v = acc[i][j][r] + bv;
                if (EPI == 0) {
                    outb[gr * Nout + gc] = f2b(v);
                } else if (EPI == 1) {
                    float gl = 0.5f * v * (1.0f + erff(v * 0.7071067811865476f));
                    outb[gr * Nout + gc] = f2b(gl);
                } else if (EPI == 2) {
                    resid[gr * 256 + gc] += v;
                } else {
                    int tok = map_token(gr, shift);
                    resid[tok * 256 + gc] += v;
                }
            }
        }
    }
}

// ---------- attention: one wave per (window, head); qkv bf16, rpb fp32 ----------
__global__ __launch_bounds__(64) void attn_kernel(const u16* __restrict__ qkv, const float* __restrict__ rpb,
                                                  u16* __restrict__ outb, int masked) {
    __shared__ float kS[64][32];
    __shared__ float vS[64][32];
    __shared__ float pS[64][65];
    __shared__ float rb[343];
    int bid = blockIdx.x;
    int win = bid >> 3, head = bid & 7;
    int t = threadIdx.x;

    const u16* base = qkv + (win * 64 + t) * 768;
    const u16* qp = base + head * 32;
    const u16* kp = base + 256 + head * 32;
    const u16* vp = base + 512 + head * 32;
    float q[32];
    #pragma unroll
    for (int cc = 0; cc < 32; cc += 8) {
        bfx8 ku = *(const bfx8*)(kp + cc);
        bfx8 vu = *(const bfx8*)(vp + cc);
        bfx8 qu = *(const bfx8*)(qp + cc);
        #pragma unroll
        for (int j = 0; j < 8; j++) {
            kS[t][cc + j] = (float)ku[j];
            vS[t][cc + j] = (float)vu[j];
            q[cc + j] = (float)qu[j];
        }
    }
    #pragma unroll
    for (int d = 0; d < 32; d++) q[d] *= 0.17677669529663687f;   // hd^-0.5
    for (int i = t; i < 343; i += 64) rb[i] = rpb[i * 8 + head];
    __syncthreads();

    int wh = win >> 6, ww = (win >> 3) & 7, wt = win & 7;
    int ih = t >> 4, iw = (t >> 2) & 3, it = t & 3;
    int labn = 0;
    if (masked) {
        int lh = (wh == 7) ? (1 + (ih >> 1)) : 0;
        int lw = (ww == 7) ? (1 + (iw >> 1)) : 0;
        int lt = (wt == 7) ? (1 + (it >> 1)) : 0;
        labn = lh * 9 + lw * 3 + lt;
    }
    int dh0 = ih + 3, dw0 = iw + 3, dt0 = it + 3;

    float mx = -1e30f;
    for (int m = 0; m < 64; m++) {
        int jh = m >> 4, jw = (m >> 2) & 3, jt = m & 3;
        const float* kr = &kS[m][0];
        float s = 0.f;
        #pragma unroll
        for (int d = 0; d < 32; d++) s += q[d] * kr[d];
        s += rb[((dh0 - jh) * 7 + (dw0 - jw)) * 7 + (dt0 - jt)];
        if (masked) {
            int lh = (wh == 7) ? (1 + (jh >> 1)) : 0;
            int lw = (ww == 7) ? (1 + (jw >> 1)) : 0;
            int lt = (wt == 7) ? (1 + (jt >> 1)) : 0;
            int labm = lh * 9 + lw * 3 + lt;
            if (labm != labn) s -= 100.0f;
        }
        pS[t][m] = s;
        mx = fmaxf(mx, s);
    }
    float sum = 0.f;
    for (int m = 0; m < 64; m++) { float e = __expf(pS[t][m] - mx); pS[t][m] = e; sum += e; }
    float inv = 1.0f / sum;
    float o[32];
    #pragma unroll
    for (int d = 0; d < 32; d++) o[d] = 0.f;
    for (int m = 0; m < 64; m++) {
        float p = pS[t][m];
        const float* vr = &vS[m][0];
        #pragma unroll
        for (int d = 0; d < 32; d++) o[d] += p * vr[d];
    }
    u32* op = (u32*)(outb + (win * 64 + t) * 256 + head * 32);
    #pragma unroll
    for (int d = 0; d < 32; d += 2) op[d >> 1] = pk(o[d] * inv, o[d + 1] * inv);
}

// ---------- [L,C] -> [C,L] fp32 transpose ----------
__global__ __launch_bounds__(256) void transpose_f32(const float* __restrict__ in, float* __restrict__ out) {
    __shared__ float tile[64][65];
    int t0 = blockIdx.x * 64;
    int c0 = blockIdx.y * 64;
    int row = threadIdx.x >> 2, cg = (threadIdx.x & 3) * 16;
    const float* src = in + (t0 + row) * 256 + c0 + cg;
    #pragma unroll
    for (int j = 0; j < 16; j += 4) {
        float4 v = *(const float4*)(src + j);
        tile[row][cg + j] = v.x; tile[row][cg + j + 1] = v.y;
        tile[row][cg + j + 2] = v.z; tile[row][cg + j + 3] = v.w;
    }
    __syncthreads();
    float tmp[16];
    #pragma unroll
    for (int j = 0; j < 16; j++) tmp[j] = tile[cg + j][row];
    float* dst = out + (c0 + row) * 32768 + t0 + cg;
    #pragma unroll
    for (int j = 0; j < 4; j++) *(float4*)(dst + 4 * j) = *(float4*)(tmp + 4 * j);
}

extern "C" void kernel_launch(void* const* d_in, const int* in_sizes, int n_in,
                              void* d_out, int out_size, void* d_ws, size_t ws_size,
                              hipStream_t stream) {
    const float* x      = (const float*)d_in[0];
    const float* norm_g = (const float*)d_in[4];
    const float* norm_b = (const float*)d_in[5];

    char* wsb = (char*)d_ws;
    float* resid = (float*)wsb;                                   // [0, 32MB)  fp32 residual
    u16*   xn    = (u16*)(wsb + (size_t)32 * 1024 * 1024);        // [32, 48MB) LN output (bf16)
    u16*   big   = (u16*)(wsb + (size_t)48 * 1024 * 1024);        // [48,112MB) qkv (48MB) / fc1 out (64MB)
    u16*   attnb = (u16*)(wsb + (size_t)96 * 1024 * 1024);        // [96,112MB) attn out (dead before fc1)
    u16*   wb    = (u16*)(wsb + (size_t)112 * 1024 * 1024);       // [112,115MB) bf16 weights
    float* xnf   = (float*)(wsb + (size_t)48 * 1024 * 1024);      // final LN fp32 (big is dead)

    // ---- convert the 8 weight matrices to bf16 (packed contiguously in wb) ----
    CvtArgs ca;
    static const int offs[9] = {0, 196608, 262144, 524288, 786432, 983040, 1048576, 1310720, 1572864};
    for (int i = 0; i < 9; i++) ca.cum[i] = offs[i];
    ca.src[0] = (const float*)d_in[6 + 2];   // wqkvw
    ca.src[1] = (const float*)d_in[6 + 5];   // wprojw
    ca.src[2] = (const float*)d_in[6 + 9];   // wfc1w
    ca.src[3] = (const float*)d_in[6 + 11];  // wfc2w
    ca.src[4] = (const float*)d_in[19 + 2];  // sqkvw
    ca.src[5] = (const float*)d_in[19 + 5];  // sprojw
    ca.src[6] = (const float*)d_in[19 + 9];  // sfc1w
    ca.src[7] = (const float*)d_in[19 + 11]; // sfc2w
    cvt_kernel<<<1536, 256, 0, stream>>>(ca, wb);

    hipMemcpyAsync(resid, x, (size_t)32768 * 256 * 4, hipMemcpyDeviceToDevice, stream);

    for (int blk = 0; blk < 2; blk++) {
        void* const* P = d_in + 6 + blk * 13;
        const float* n1g  = (const float*)P[0];
        const float* n1b  = (const float*)P[1];
        const float* qkvb = (const float*)P[3];
        const float* rpb  = (const float*)P[4];
        const float* pjb  = (const float*)P[6];
        const float* n2g  = (const float*)P[7];
        const float* n2b  = (const float*)P[8];
        const float* f1b  = (const float*)P[10];
        const float* f2b_ = (const float*)P[12];
        const u16* qkvw = wb + offs[0] + blk * 786432;
        const u16* pjw  = wb + offs[1] + blk * 786432;
        const u16* f1w  = wb + offs[2] + blk * 786432;
        const u16* f2w  = wb + offs[3] + blk * 786432;
        int shift = blk ? 2 : 0;

        ln_kernel<1, 0><<<8192, 256, 0, stream>>>(resid, n1g, n1b, xn, shift);
        gemm_kernel<0><<<dim3(512, 12), 256, 0, stream>>>(xn, qkvw, qkvb, big, nullptr, 768, 256, 0);
        attn_kernel<<<4096, 64, 0, stream>>>(big, rpb, attnb, blk);
        gemm_kernel<3><<<dim3(512, 4), 256, 0, stream>>>(attnb, pjw, pjb, nullptr, resid, 256, 256, shift);
        ln_kernel<0, 0><<<8192, 256, 0, stream>>>(resid, n2g, n2b, xn, 0);
        gemm_kernel<1><<<dim3(512, 16), 256, 0, stream>>>(xn, f1w, f1b, big, nullptr, 1024, 256, 0);
        gemm_kernel<2><<<dim3(512, 4), 256, 0, stream>>>(big, f2w, f2b_, nullptr, resid, 256, 1024, 0);
    }

    ln_kernel<0, 1><<<8192, 256, 0, stream>>>(resid, norm_g, norm_b, xnf, 0);
    transpose_f32<<<dim3(512, 4), 256, 0, stream>>>(xnf, (float*)d_out);
}

// Round 3
// 513.420 us; speedup vs baseline: 2.3069x; 2.3069x over previous
//
#include <hip/hip_runtime.h>

typedef unsigned short u16;
typedef unsigned int   u32;
typedef __bf16 bfx8 __attribute__((ext_vector_type(8)));
typedef float  fx4  __attribute__((ext_vector_type(4)));

__device__ __forceinline__ u16 f2b(float f) {
    union { float f; u32 i; } v; v.f = f;
    u32 r = (v.i + 0x7fffu + ((v.i >> 16) & 1u)) >> 16;
    return (u16)r;
}
__device__ __forceinline__ u32 pk(float a, float b) {
    return (u32)f2b(a) | ((u32)f2b(b) << 16);
}

__device__ __forceinline__ void gl2lds16(const u16* g, u16* l) {
    __builtin_amdgcn_global_load_lds(
        (const __attribute__((address_space(1))) u32*)(const void*)g,
        (__attribute__((address_space(3))) u32*)(void*)l, 16, 0, 0);
}

// partitioned row r (window-major) -> token index in [0,32768), with roll shift
__device__ __forceinline__ int map_token(int r, int shift) {
    int win = r >> 6, n = r & 63;
    int wh = win >> 6, ww = (win >> 3) & 7, wt = win & 7;
    int h = wh * 4 + (n >> 4);
    int w = ww * 4 + ((n >> 2) & 3);
    int t = wt * 4 + (n & 3);
    h = (h + shift) & 31; w = (w + shift) & 31; t = (t + shift) & 31;
    return (h << 10) | (w << 5) | t;
}

// ---------- batched fp32 -> bf16 weight conversion ----------
struct CvtArgs { const float* src[8]; int cum[9]; };
__global__ __launch_bounds__(256) void cvt_kernel(CvtArgs a, u16* __restrict__ dst) {
    int g = (blockIdx.x * 256 + threadIdx.x) * 4;
    int t = 0;
    #pragma unroll
    for (int i = 1; i < 8; i++) t += (g >= a.cum[i]);
    int local = g - a.cum[t];
    float4 f = *(const float4*)(a.src[t] + local);
    uint2 o; o.x = pk(f.x, f.y); o.y = pk(f.z, f.w);
    *(uint2*)(dst + g) = o;
}

// ---------- LayerNorm (one wave per token) ----------
template<int GATHER, int F32OUT>
__global__ __launch_bounds__(256) void ln_kernel(const float* __restrict__ resid,
                                                 const float* __restrict__ g, const float* __restrict__ b,
                                                 void* __restrict__ outp, int shift) {
    int lane = threadIdx.x & 63;
    int row  = blockIdx.x * 4 + (threadIdx.x >> 6);
    int src  = GATHER ? map_token(row, shift) : row;
    float4 x = ((const float4*)(resid + src * 256))[lane];
    float s1 = x.x + x.y + x.z + x.w;
    float s2 = x.x * x.x + x.y * x.y + x.z * x.z + x.w * x.w;
    #pragma unroll
    for (int off = 1; off < 64; off <<= 1) { s1 += __shfl_xor(s1, off); s2 += __shfl_xor(s2, off); }
    float mean = s1 * (1.0f / 256.0f);
    float var  = s2 * (1.0f / 256.0f) - mean * mean;
    float rstd = rsqrtf(var + 1e-5f);
    int c = lane * 4;
    float4 gv = *(const float4*)(g + c);
    float4 bv = *(const float4*)(b + c);
    float y0 = (x.x - mean) * rstd * gv.x + bv.x;
    float y1 = (x.y - mean) * rstd * gv.y + bv.y;
    float y2 = (x.z - mean) * rstd * gv.z + bv.z;
    float y3 = (x.w - mean) * rstd * gv.w + bv.w;
    if (F32OUT) {
        float4 o; o.x = y0; o.y = y1; o.z = y2; o.w = y3;
        *(float4*)((float*)outp + row * 256 + c) = o;
    } else {
        uint2 o; o.x = pk(y0, y1); o.y = pk(y2, y3);
        *(uint2*)((u16*)outp + row * 256 + c) = o;
    }
}

// ---------- GEMM: C[M,N] = A[M,K] @ W[N,K]^T + bias (bf16 MFMA, LDS-staged) ----------
// 128x128 tile, BK=32, global_load_lds w/ XOR-swizzled granules.
// EPI 0: bf16 store; 1: GELU + bf16 store; 2: resid += ; 3: resid[map_token] +=
template<int EPI>
__global__ __launch_bounds__(256) void gemm2(const u16* __restrict__ A, const u16* __restrict__ W,
                                             const float* __restrict__ bias,
                                             u16* __restrict__ outb, float* __restrict__ resid,
                                             int Nout, int K, int shift) {
    __shared__ u16 As[128 * 32];
    __shared__ u16 Bs[128 * 32];
    int lane = threadIdx.x & 63, w = threadIdx.x >> 6;
    int wm = w >> 1, wn = w & 1;
    int m0 = blockIdx.x * 128, n0 = blockIdx.y * 128;
    int lr = lane & 15, q = lane >> 4;
    int sw = q ^ ((lr >> 1) & 3);          // frag-read swizzle (uniform over tiles)

    fx4 acc[4][4] = {};

    for (int kt = 0; kt < K; kt += 32) {
        __syncthreads();
        #pragma unroll
        for (int p = 0; p < 2; p++) {
            int row = p * 64 + w * 16 + (lane >> 2);
            int kg  = (lane & 3) ^ ((row >> 1) & 3);
            int slot = (p * 256 + w * 64 + lane) * 8;   // u16 index (16B granules)
            gl2lds16(A + (size_t)(m0 + row) * K + kt + kg * 8, As + slot);
            gl2lds16(W + (size_t)(n0 + row) * K + kt + kg * 8, Bs + slot);
        }
        __syncthreads();
        bfx8 af[4], bfr[4];
        #pragma unroll
        for (int t = 0; t < 4; t++) {
            int ra = wm * 64 + t * 16 + lr;
            int rb = wn * 64 + t * 16 + lr;
            af[t]  = *(const bfx8*)(As + (ra * 4 + sw) * 8);
            bfr[t] = *(const bfx8*)(Bs + (rb * 4 + sw) * 8);
        }
        #pragma unroll
        for (int i = 0; i < 4; i++)
            #pragma unroll
            for (int j = 0; j < 4; j++)
                acc[i][j] = __builtin_amdgcn_mfma_f32_16x16x32_bf16(af[i], bfr[j], acc[i][j], 0, 0, 0);
    }

    float bv[4];
    #pragma unroll
    for (int j = 0; j < 4; j++) bv[j] = bias[n0 + wn * 64 + j * 16 + lr];
    #pragma unroll
    for (int i = 0; i < 4; i++) {
        #pragma unroll
        for (int r = 0; r < 4; r++) {
            int gr = m0 + wm * 64 + i * 16 + q * 4 + r;
            int orow = (EPI == 3) ? map_token(gr, shift) : gr;
            #pragma unroll
            for (int j = 0; j < 4; j++) {
                int gc = n0 + wn * 64 + j * 16 + lr;
                float v = acc[i][j][r] + bv[j];
                if (EPI == 0) {
                    outb[(size_t)gr * Nout + gc] = f2b(v);
                } else if (EPI == 1) {
                    float gl = 0.5f * v * (1.0f + erff(v * 0.7071067811865476f));
                    outb[(size_t)gr * Nout + gc] = f2b(gl);
                } else {
                    resid[orow * 256 + gc] += v;
                }
            }
        }
    }
}

// ---------- MFMA attention: one wave per (window, head), 2 waves/block ----------
__global__ __launch_bounds__(128) void attn_mfma(const u16* __restrict__ qkv, const float* __restrict__ rpb,
                                                 u16* __restrict__ outb, int masked) {
    __shared__ u16  Pl[2][64][72];
    __shared__ u16  VT[2][32][72];
    __shared__ float rbS[2][344];
    int w = threadIdx.x >> 6;
    int lane = threadIdx.x & 63;
    int id = blockIdx.x * 2 + w;
    int win = id >> 3, head = id & 7;
    int lr = lane & 15, q = lane >> 4;

    const u16* base = qkv + (size_t)win * 64 * 768 + head * 32;

    // Q (B-operand) and K (A-operand) fragments: row lr+16t, d = q*8..+7
    bfx8 qf[4], kf[4];
    #pragma unroll
    for (int t = 0; t < 4; t++) {
        const u16* rq = base + (lr + 16 * t) * 768 + q * 8;
        qf[t] = *(const bfx8*)(rq);
        kf[t] = *(const bfx8*)(rq + 256);
    }
    // V -> VT[d][m] (transposed staging for B-operand contiguity)
    {
        const u16* rv = base + lane * 768 + 512;
        #pragma unroll
        for (int c = 0; c < 32; c += 8) {
            bfx8 vv = *(const bfx8*)(rv + c);
            #pragma unroll
            for (int j = 0; j < 8; j++) VT[w][c + j][lane] = ((const u16*)&vv)[j];
        }
    }
    for (int i = lane; i < 343; i += 64) rbS[w][i] = rpb[i * 8 + head];

    // S^T[j][i] = sum_d K[j][d] Q[i][d] : 16 MFMAs, K-dim = hd = 32 (one step)
    fx4 sT[4][4] = {};
    #pragma unroll
    for (int jt = 0; jt < 4; jt++)
        #pragma unroll
        for (int it = 0; it < 4; it++)
            sT[jt][it] = __builtin_amdgcn_mfma_f32_16x16x32_bf16(kf[jt], qf[it], sT[jt][it], 0, 0, 0);

    int wh = win >> 6, ww = (win >> 3) & 7, wt = win & 7;
    const float scale = 0.17677669529663687f;   // hd^-0.5

    // softmax over key index j (rows of S^T). Lane holds col i = lr+16it,
    // rows j = q*4+r+16jt -> full row set covered across quads; reduce via shfl 16,32.
    #pragma unroll
    for (int it = 0; it < 4; it++) {
        int i = lr + 16 * it;
        int ih = i >> 4, iw = (i >> 2) & 3, iT = i & 3;
        int labn = 0;
        if (masked) {
            int lh = (wh == 7) ? (1 + (ih >> 1)) : 0;
            int lw = (ww == 7) ? (1 + (iw >> 1)) : 0;
            int lt = (wt == 7) ? (1 + (iT >> 1)) : 0;
            labn = lh * 9 + lw * 3 + lt;
        }
        float sv[4][4];
        float mx = -1e30f;
        #pragma unroll
        for (int jt = 0; jt < 4; jt++)
            #pragma unroll
            for (int r = 0; r < 4; r++) {
                int j = q * 4 + r + 16 * jt;
                int jh = j >> 4, jw = (j >> 2) & 3, jT = j & 3;
                float s = sT[jt][it][r] * scale +
                          rbS[w][((ih - jh + 3) * 7 + (iw - jw + 3)) * 7 + (iT - jT + 3)];
                if (masked) {
                    int lh = (wh == 7) ? (1 + (jh >> 1)) : 0;
                    int lw = (ww == 7) ? (1 + (jw >> 1)) : 0;
                    int lt = (wt == 7) ? (1 + (jT >> 1)) : 0;
                    if (lh * 9 + lw * 3 + lt != labn) s -= 100.0f;
                }
                sv[jt][r] = s;
                mx = fmaxf(mx, s);
            }
        mx = fmaxf(mx, __shfl_xor(mx, 16));
        mx = fmaxf(mx, __shfl_xor(mx, 32));
        float sum = 0.f;
        #pragma unroll
        for (int jt = 0; jt < 4; jt++)
            #pragma unroll
            for (int r = 0; r < 4; r++) { sv[jt][r] = __expf(sv[jt][r] - mx); sum += sv[jt][r]; }
        sum += __shfl_xor(sum, 16);
        sum += __shfl_xor(sum, 32);
        float inv = 1.0f / sum;
        #pragma unroll
        for (int jt = 0; jt < 4; jt++) {
            uint2 pw;
            pw.x = pk(sv[jt][0] * inv, sv[jt][1] * inv);
            pw.y = pk(sv[jt][2] * inv, sv[jt][3] * inv);
            *(uint2*)&Pl[w][i][q * 4 + 16 * jt] = pw;   // P[i][j], j = q*4+16jt+r consecutive
        }
    }

    // O[i][d] = sum_m P[i][m] V[m][d] : A = P rows (LDS), B = VT rows (LDS)
    fx4 o[4][2] = {};
    #pragma unroll
    for (int kk = 0; kk < 2; kk++) {
        bfx8 pf[4], vf[2];
        #pragma unroll
        for (int it = 0; it < 4; it++) pf[it] = *(const bfx8*)&Pl[w][lr + 16 * it][q * 8 + 32 * kk];
        #pragma unroll
        for (int dt = 0; dt < 2; dt++) vf[dt] = *(const bfx8*)&VT[w][lr + 16 * dt][q * 8 + 32 * kk];
        #pragma unroll
        for (int it = 0; it < 4; it++)
            #pragma unroll
            for (int dt = 0; dt < 2; dt++)
                o[it][dt] = __builtin_amdgcn_mfma_f32_16x16x32_bf16(pf[it], vf[dt], o[it][dt], 0, 0, 0);
    }

    u16* ob = outb + (size_t)win * 64 * 256 + head * 32;
    #pragma unroll
    for (int it = 0; it < 4; it++)
        #pragma unroll
        for (int r = 0; r < 4; r++) {
            int i = 16 * it + q * 4 + r;
            #pragma unroll
            for (int dt = 0; dt < 2; dt++)
                ob[i * 256 + 16 * dt + lr] = f2b(o[it][dt][r]);
        }
}

// ---------- [L,C] -> [C,L] fp32 transpose ----------
__global__ __launch_bounds__(256) void transpose_f32(const float* __restrict__ in, float* __restrict__ out) {
    __shared__ float tile[64][65];
    int t0 = blockIdx.x * 64;
    int c0 = blockIdx.y * 64;
    int row = threadIdx.x >> 2, cg = (threadIdx.x & 3) * 16;
    const float* src = in + (t0 + row) * 256 + c0 + cg;
    #pragma unroll
    for (int j = 0; j < 16; j += 4) {
        float4 v = *(const float4*)(src + j);
        tile[row][cg + j] = v.x; tile[row][cg + j + 1] = v.y;
        tile[row][cg + j + 2] = v.z; tile[row][cg + j + 3] = v.w;
    }
    __syncthreads();
    float tmp[16];
    #pragma unroll
    for (int j = 0; j < 16; j++) tmp[j] = tile[cg + j][row];
    float* dst = out + (c0 + row) * 32768 + t0 + cg;
    #pragma unroll
    for (int j = 0; j < 4; j++) *(float4*)(dst + 4 * j) = *(float4*)(tmp + 4 * j);
}

extern "C" void kernel_launch(void* const* d_in, const int* in_sizes, int n_in,
                              void* d_out, int out_size, void* d_ws, size_t ws_size,
                              hipStream_t stream) {
    const float* x      = (const float*)d_in[0];
    const float* norm_g = (const float*)d_in[4];
    const float* norm_b = (const float*)d_in[5];

    char* wsb = (char*)d_ws;
    float* resid = (float*)wsb;                                   // [0, 32MB)  fp32 residual
    u16*   xn    = (u16*)(wsb + (size_t)32 * 1024 * 1024);        // [32, 48MB) LN output (bf16)
    u16*   big   = (u16*)(wsb + (size_t)48 * 1024 * 1024);        // [48,112MB) qkv (48MB) / fc1 out (64MB)
    u16*   attnb = (u16*)(wsb + (size_t)96 * 1024 * 1024);        // [96,112MB) attn out (dead before fc1)
    u16*   wb    = (u16*)(wsb + (size_t)112 * 1024 * 1024);       // [112,115MB) bf16 weights
    float* xnf   = (float*)(wsb + (size_t)48 * 1024 * 1024);      // final LN fp32 (big is dead)

    CvtArgs ca;
    static const int offs[9] = {0, 196608, 262144, 524288, 786432, 983040, 1048576, 1310720, 1572864};
    for (int i = 0; i < 9; i++) ca.cum[i] = offs[i];
    ca.src[0] = (const float*)d_in[6 + 2];   // wqkvw
    ca.src[1] = (const float*)d_in[6 + 5];   // wprojw
    ca.src[2] = (const float*)d_in[6 + 9];   // wfc1w
    ca.src[3] = (const float*)d_in[6 + 11];  // wfc2w
    ca.src[4] = (const float*)d_in[19 + 2];  // sqkvw
    ca.src[5] = (const float*)d_in[19 + 5];  // sprojw
    ca.src[6] = (const float*)d_in[19 + 9];  // sfc1w
    ca.src[7] = (const float*)d_in[19 + 11]; // sfc2w
    cvt_kernel<<<1536, 256, 0, stream>>>(ca, wb);

    hipMemcpyAsync(resid, x, (size_t)32768 * 256 * 4, hipMemcpyDeviceToDevice, stream);

    for (int blk = 0; blk < 2; blk++) {
        void* const* P = d_in + 6 + blk * 13;
        const float* n1g  = (const float*)P[0];
        const float* n1b  = (const float*)P[1];
        const float* qkvb = (const float*)P[3];
        const float* rpb  = (const float*)P[4];
        const float* pjb  = (const float*)P[6];
        const float* n2g  = (const float*)P[7];
        const float* n2b  = (const float*)P[8];
        const float* f1b  = (const float*)P[10];
        const float* f2b_ = (const float*)P[12];
        const u16* qkvw = wb + offs[0] + blk * 786432;
        const u16* pjw  = wb + offs[1] + blk * 786432;
        const u16* f1w  = wb + offs[2] + blk * 786432;
        const u16* f2w  = wb + offs[3] + blk * 786432;
        int shift = blk ? 2 : 0;

        ln_kernel<1, 0><<<8192, 256, 0, stream>>>(resid, n1g, n1b, xn, shift);
        gemm2<0><<<dim3(256, 6), 256, 0, stream>>>(xn, qkvw, qkvb, big, nullptr, 768, 256, 0);
        attn_mfma<<<2048, 128, 0, stream>>>(big, rpb, attnb, blk);
        gemm2<3><<<dim3(256, 2), 256, 0, stream>>>(attnb, pjw, pjb, nullptr, resid, 256, 256, shift);
        ln_kernel<0, 0><<<8192, 256, 0, stream>>>(resid, n2g, n2b, xn, 0);
        gemm2<1><<<dim3(256, 8), 256, 0, stream>>>(xn, f1w, f1b, big, nullptr, 1024, 256, 0);
        gemm2<2><<<dim3(256, 2), 256, 0, stream>>>(big, f2w, f2b_, nullptr, resid, 256, 1024, 0);
    }

    ln_kernel<0, 1><<<8192, 256, 0, stream>>>(resid, norm_g, norm_b, xnf, 0);
    transpose_f32<<<dim3(512, 4), 256, 0, stream>>>(xnf, (float*)d_out);
}